// Round 1
// 245.788 us; speedup vs baseline: 1.0141x; 1.0141x over previous
//
#include <hip/hip_runtime.h>
#include <hip/hip_bf16.h>
#include <stdint.h>

#define MD   128
#define LBAS 256

// ws layout: NkFull fp32 (256x128) @0, Mbf bf16 (128x128) @131072
#define MBF_OFF 131072ull
#define WS_NEED (131072ull + 32768ull)

typedef __attribute__((ext_vector_type(8))) __bf16 bf16x8;
typedef __attribute__((ext_vector_type(4))) float floatx4;
typedef __attribute__((ext_vector_type(8))) unsigned short ushortx8;
typedef __attribute__((ext_vector_type(4))) unsigned short ushortx4;

__device__ __forceinline__ float bf2f(unsigned short u){
  union { unsigned int i; float f; } v; v.i = ((unsigned int)u) << 16; return v.f;
}
__device__ __forceinline__ unsigned short f2bf(float x){
  union { float f; unsigned int i; } v; v.f = x;
  unsigned int r = v.i + 0x7FFFu + ((v.i >> 16) & 1u);
  return (unsigned short)(r >> 16);
}
__device__ __forceinline__ int detect_f32(const void* Bbasis){
  return ((const unsigned int*)Bbasis)[0] == 0x3F800000u;   // cos(pi)^4 == 1.0f
}

// ================= K0: Nk table + M->bf16 =================
__global__ __launch_bounds__(256) void nk2_kernel(const void* __restrict__ Acoeff,
                                                  const void* __restrict__ Bbasis,
                                                  const void* __restrict__ Mmat,
                                                  float* __restrict__ NkFull,
                                                  unsigned short* __restrict__ Mbf){
  int gid = blockIdx.x * 256 + threadIdx.x;
  const int isf = detect_f32(Bbasis);
  if (gid < LBAS * MD){
    int idx = gid >> 7, j = gid & 127;
    float a, b;
    if (isf){ a = ((const float*)Acoeff)[j*LBAS+idx]; b = ((const float*)Bbasis)[idx*MD+j]; }
    else    { a = bf2f(((const unsigned short*)Acoeff)[j*LBAS+idx]);
              b = bf2f(((const unsigned short*)Bbasis)[idx*MD+j]); }
    NkFull[gid] = a * b;
  } else {
    int m = gid - LBAS * MD;
    if (m < MD * MD){
      Mbf[m] = isf ? f2bf(((const float*)Mmat)[m]) : ((const unsigned short*)Mmat)[m];
    }
  }
}

// ================= K1: fused pool(2^4) + GEMM + epilogue =================
// block = (b, w2, w3); loop x1=0..15; pooled-234 ping-pong in LDS;
// A = avg of consecutive x1 slabs; MFMA vs per-thread REGISTER M fragments.
// M dropped from LDS (loop-invariant -> 16 VGPRs/thread, loaded once from L2).
// LDS = 16896(S/Ct) + 8160(pp) + 4352(Ab) + 2048(Nk) = 31456 B -> 4 blocks/CU
// (VGPR-capped at 4 waves/SIMD via __launch_bounds__(256,4); was 2 blocks/CU).
__global__ __launch_bounds__(256, 4) void mega_kernel(const void* __restrict__ vec,
                                                      const float* __restrict__ NkFull,
                                                      const unsigned short* __restrict__ Mbf,
                                                      const void* __restrict__ Bbasis,
                                                      void* __restrict__ out){
  __shared__ __align__(16) float S[32 * 132];                  // staging; aliased as Ct
  __shared__ __align__(16) unsigned short pp[2][15][136];      // pooled-234 ping-pong (bf16)
  __shared__ __align__(16) unsigned short Ab[16 * 136];        // A-tile (row 15 unused)
  __shared__ __align__(16) float sNkStep[512];                 // 4 j4-rows x 128

  // --- block decode: XCD-group same-b blocks (xcd = bid&7 -> {2b,2b+1}) ---
  const int xcd  = blockIdx.x & 7;
  const int slot = blockIdx.x >> 3;
  const int b    = xcd >> 1;
  const int s    = slot * 2 + (xcd & 1);
  if (s >= 225) return;
  const int w3 = s / 15;
  const int w2 = s - w3 * 15;
  const int t  = threadIdx.x;
  const int isf = detect_f32(Bbasis);

  const int wave = t >> 6, lane = t & 63;
  const int quad = lane >> 4, l16 = lane & 15;

  // vec strides (elems): b 8388608, x1 524288, x2 32768, x3 2048, x4 128
  const size_t vbase0 = (size_t)b * 8388608 + (size_t)w2 * 32768 + (size_t)w3 * 2048;

  // --- per-thread static offsets ---
  int offF[4];   // fp32: 4 float4-chunks
#pragma unroll
  for (int k = 0; k < 4; ++k){
    const int ci = k * 256 + t;          // 0..1023
    const int row = ci >> 5;             // x3sub*16 + x4
    offF[k] = (row >> 4) * 2048 + (row & 15) * 128 + (ci & 31) * 4;
  }
  int offB[2];   // bf16: 2 ushortx8-chunks
#pragma unroll
  for (int k = 0; k < 2; ++k){
    const int ci = k * 256 + t;          // 0..511
    const int row = ci >> 4;
    offB[k] = (row >> 4) * 2048 + (row & 15) * 128 + (ci & 15) * 8;
  }

  floatx4 pre[4][2];   // prefetch regs (bf16 path bit-casts into pre[0..1])

  // --- prefetch x1 = 0 (issue HBM loads first) ---
  if (isf){
    const float* vf = (const float*)vec + vbase0;
#pragma unroll
    for (int k = 0; k < 4; ++k){
      pre[k][0] = *(const floatx4*)(vf + offF[k]);
      pre[k][1] = *(const floatx4*)(vf + offF[k] + 32768);
    }
  } else {
    const unsigned short* vh = (const unsigned short*)vec + vbase0;
#pragma unroll
    for (int k = 0; k < 2; ++k){
      *(ushortx8*)&pre[k][0] = *(const ushortx8*)(vh + offB[k]);
      *(ushortx8*)&pre[k][1] = *(const ushortx8*)(vh + offB[k] + 32768);
    }
  }

  // --- M fragments -> registers (loop-invariant; 16 VGPRs; L2-hot source) ---
  // mfr[cc][s4] = M rows (wave*2+cc)*16+l16, cols s4*32+quad*8 .. +7
  bf16x8 mfr[2][4];
#pragma unroll
  for (int cc = 0; cc < 2; ++cc)
#pragma unroll
    for (int s4 = 0; s4 < 4; ++s4)
      *(ushortx8*)&mfr[cc][s4] =
          *(const ushortx8*)(Mbf + ((wave * 2 + cc) * 16 + l16) * 128 + s4 * 32 + quad * 8);

  const int pw4 = t >> 4;            // pooling coords (t<240 active)
  const int pc8 = (t & 15) * 8;

  for (int x1 = 0; x1 < 16; ++x1){
    __syncthreads();   // S free (prev stores done)

    // ---- regs -> S (x2-pair sum) ----
    if (isf){
#pragma unroll
      for (int k = 0; k < 4; ++k){
        const int ci = k * 256 + t;
        const int row = ci >> 5, c4 = (ci & 31) * 4;
        floatx4 sv;
#pragma unroll
        for (int q = 0; q < 4; ++q) sv[q] = pre[k][0][q] + pre[k][1][q];
        *(floatx4*)&S[row * 132 + c4] = sv;
      }
    } else {
#pragma unroll
      for (int k = 0; k < 2; ++k){
        const int ci = k * 256 + t;
        const int row = ci >> 4, c8 = (ci & 15) * 8;
        const ushortx8 a = *(const ushortx8*)&pre[k][0];
        const ushortx8 c = *(const ushortx8*)&pre[k][1];
#pragma unroll
        for (int q = 0; q < 8; ++q) S[row * 132 + c8 + q] = bf2f(a[q]) + bf2f(c[q]);
      }
    }

    // ---- prefetch x1+1 (overlaps everything below) ----
    if (x1 < 15){
      if (isf){
        const float* vf = (const float*)vec + vbase0 + (size_t)(x1 + 1) * 524288;
#pragma unroll
        for (int k = 0; k < 4; ++k){
          pre[k][0] = *(const floatx4*)(vf + offF[k]);
          pre[k][1] = *(const floatx4*)(vf + offF[k] + 32768);
        }
      } else {
        const unsigned short* vh = (const unsigned short*)vec + vbase0 + (size_t)(x1 + 1) * 524288;
#pragma unroll
        for (int k = 0; k < 2; ++k){
          *(ushortx8*)&pre[k][0] = *(const ushortx8*)(vh + offB[k]);
          *(ushortx8*)&pre[k][1] = *(const ushortx8*)(vh + offB[k] + 32768);
        }
      }
    }
    __syncthreads();   // S ready

    // ---- pool x3,x4 (2x2) + A-tile build ----
    const int cb = x1 & 1, pbuf = cb ^ 1;
    if (t < 240){
      float cur[8];
      const int p0 = pw4 * 132 + pc8;
#pragma unroll
      for (int e = 0; e < 8; ++e)
        cur[e] = ((S[p0 + e] + S[p0 + 132 + e]) +
                  (S[p0 + 16 * 132 + e] + S[p0 + 17 * 132 + e])) * 0.125f;
      ushortx8 cv;
#pragma unroll
      for (int e = 0; e < 8; ++e) cv[e] = f2bf(cur[e]);
      *(ushortx8*)&pp[cb][pw4][pc8] = cv;
      if (x1 > 0){
        const ushortx8 pv = *(const ushortx8*)&pp[pbuf][pw4][pc8];
        ushortx8 av;
#pragma unroll
        for (int e = 0; e < 8; ++e) av[e] = f2bf((cur[e] + bf2f(pv[e])) * 0.5f);
        *(ushortx8*)&Ab[pw4 * 136 + pc8] = av;
      }
    }
    __syncthreads();   // Ab ready (S consumed)

    if (x1 > 0){
      // ---- MFMA: wave w -> col tiles {2w, 2w+1}; B from registers ----
      floatx4 acc[2];
      acc[0] = (floatx4){0.f,0.f,0.f,0.f};
      acc[1] = (floatx4){0.f,0.f,0.f,0.f};
#pragma unroll
      for (int s4 = 0; s4 < 4; ++s4){
        const bf16x8 af = *(const bf16x8*)&Ab[l16 * 136 + s4 * 32 + quad * 8];
#pragma unroll
        for (int cc = 0; cc < 2; ++cc){
          acc[cc] = __builtin_amdgcn_mfma_f32_16x16x32_bf16(af, mfr[cc][s4], acc[cc], 0, 0, 0);
        }
      }
      // ---- Ct (aliases S) + Nk stage ----
      float* Ct = S;
#pragma unroll
      for (int cc = 0; cc < 2; ++cc)
#pragma unroll
        for (int reg = 0; reg < 4; ++reg)
          Ct[(quad * 4 + reg) * 132 + (wave * 2 + cc) * 16 + l16] = acc[cc][reg];

      const int j1 = (x1 - 1) & 3;
      const int idxBase = ((j1 * 4 + (w2 & 3)) * 4 + (w3 & 3)) * 4;
#pragma unroll
      for (int k = 0; k < 2; ++k){
        const int e = k * 256 + t;
        sNkStep[e] = NkFull[(idxBase + (e >> 7)) * 128 + (e & 127)];
      }
      __syncthreads();   // Ct + Nk ready

      // ---- coalesced stores: 15 rows x 512 B contiguous ----
      const size_t outBase = ((size_t)(((b * 15 + (x1 - 1)) * 15 + w2) * 15 + w3)) * 15;
#pragma unroll
      for (int k = 0; k < 2; ++k){
        const int ci = k * 256 + t;
        if (ci < 480){
          const int row = ci >> 5, c4 = (ci & 31) * 4;
          const floatx4 v  = *(const floatx4*)&Ct[row * 132 + c4];
          const floatx4 nk = *(const floatx4*)&sNkStep[(row & 3) * 128 + c4];
          floatx4 o;
#pragma unroll
          for (int e = 0; e < 4; ++e) o[e] = nk[e] - v[e];
          if (isf){
            *(floatx4*)((float*)out + (outBase + row) * 128 + c4) = o;
          } else {
            ushortx4 ob;
#pragma unroll
            for (int e = 0; e < 4; ++e) ob[e] = f2bf(o[e]);
            *(ushortx4*)((unsigned short*)out + (outBase + row) * 128 + c4) = ob;
          }
        }
      }
    }
  }
}

extern "C" void kernel_launch(void* const* d_in, const int* in_sizes, int n_in,
                              void* d_out, int out_size, void* d_ws, size_t ws_size,
                              hipStream_t stream) {
  const void* vec = d_in[0];   // (4,16,16,16,16,128)
  const void* Mm  = d_in[1];   // (128,128)
  const void* Ac  = d_in[2];   // (128,256)
  const void* Bb  = d_in[3];   // (256,128)

  float* NkFull = (float*)d_ws;
  unsigned short* Mbf = (unsigned short*)((char*)d_ws + MBF_OFF);

  nk2_kernel<<<192, 256, 0, stream>>>(Ac, Bb, Mm, NkFull, Mbf);
  mega_kernel<<<904, 256, 0, stream>>>(vec, NkFull, Mbf, Bb, d_out);
}